// Round 3
// baseline (441.782 us; speedup 1.0000x reference)
//
#include <hip/hip_runtime.h>

// Input:  (16, 1, 2048, 2048) fp32
// Output: low  (16, 1, 1024, 1024) fp32  — LL
//         high (16, 3, 1024, 1024) fp32  — LH, HL, HH
// d_out = [low | high] flat.
//
// Each thread: 4 output pixels. Loads 2x 16B from each of 2 input rows
// (coalesced), writes 1x 16B to each of the 4 subbands (coalesced,
// non-temporal: pure streaming store, no reuse).
// Uses native ext_vector_type (HIP_vector_type is a struct — rejected by
// __builtin_nontemporal_store).

#define B   16
#define H   2048
#define W   2048
#define HO  1024
#define WO  1024

typedef float v4f __attribute__((ext_vector_type(4)));

__global__ __launch_bounds__(256) void dwt_haar_kernel(
    const float* __restrict__ x, float* __restrict__ out)
{
    // total threads = B * HO * (WO/4) = 16 * 1024 * 256 = 4,194,304
    const unsigned tid = blockIdx.x * blockDim.x + threadIdx.x;
    const int j4 = tid & 255;          // v4f column index [0,256)
    const int i  = (tid >> 8) & 1023;  // output row
    const int b  = tid >> 18;          // batch

    const size_t in_base = (size_t)b * H * W + (size_t)(2 * i) * W + 8 * (size_t)j4;
    const v4f r0a = *(const v4f*)(x + in_base);         // a0 b0 a1 b1
    const v4f r0b = *(const v4f*)(x + in_base + 4);     // a2 b2 a3 b3
    const v4f r1a = *(const v4f*)(x + in_base + W);     // c0 d0 c1 d1
    const v4f r1b = *(const v4f*)(x + in_base + W + 4); // c2 d2 c3 d3

    // butterfly factored: s = a+c, t = b+d, u = a-c, v = b-d
    const float s0 = r0a.x + r1a.x, t0 = r0a.y + r1a.y;
    const float u0 = r0a.x - r1a.x, v0 = r0a.y - r1a.y;
    const float s1 = r0a.z + r1a.z, t1 = r0a.w + r1a.w;
    const float u1 = r0a.z - r1a.z, v1 = r0a.w - r1a.w;
    const float s2 = r0b.x + r1b.x, t2 = r0b.y + r1b.y;
    const float u2 = r0b.x - r1b.x, v2 = r0b.y - r1b.y;
    const float s3 = r0b.z + r1b.z, t3 = r0b.w + r1b.w;
    const float u3 = r0b.z - r1b.z, v3 = r0b.w - r1b.w;

    v4f LL, LH, HL, HH;
    LL.x = (s0 + t0) * 0.5f; LL.y = (s1 + t1) * 0.5f;
    LL.z = (s2 + t2) * 0.5f; LL.w = (s3 + t3) * 0.5f;
    LH.x = (u0 + v0) * 0.5f; LH.y = (u1 + v1) * 0.5f;
    LH.z = (u2 + v2) * 0.5f; LH.w = (u3 + v3) * 0.5f;
    HL.x = (s0 - t0) * 0.5f; HL.y = (s1 - t1) * 0.5f;
    HL.z = (s2 - t2) * 0.5f; HL.w = (s3 - t3) * 0.5f;
    HH.x = (u0 - v0) * 0.5f; HH.y = (u1 - v1) * 0.5f;
    HH.z = (u2 - v2) * 0.5f; HH.w = (u3 - v3) * 0.5f;

    const size_t plane = (size_t)HO * WO;          // 1,048,576
    const size_t row_off = (size_t)i * WO;

    float* low  = out;                              // (B,1,HO,WO)
    float* high = out + (size_t)B * plane;          // (B,3,HO,WO)

    __builtin_nontemporal_store(LL, (v4f*)(low  + (size_t)b * plane           + row_off) + j4);
    __builtin_nontemporal_store(LH, (v4f*)(high + (size_t)(b * 3 + 0) * plane + row_off) + j4);
    __builtin_nontemporal_store(HL, (v4f*)(high + (size_t)(b * 3 + 1) * plane + row_off) + j4);
    __builtin_nontemporal_store(HH, (v4f*)(high + (size_t)(b * 3 + 2) * plane + row_off) + j4);
}

extern "C" void kernel_launch(void* const* d_in, const int* in_sizes, int n_in,
                              void* d_out, int out_size, void* d_ws, size_t ws_size,
                              hipStream_t stream) {
    const float* x = (const float*)d_in[0];
    float* out = (float*)d_out;

    const int total_threads = B * HO * (WO / 4);   // 4,194,304
    const int block = 256;
    const int grid = total_threads / block;        // 16,384

    dwt_haar_kernel<<<grid, block, 0, stream>>>(x, out);
}